// Round 11
// baseline (212.316 us; speedup 1.0000x reference)
//
#include <hip/hip_runtime.h>
#include <hip/hip_bf16.h>
#include <math.h>

#define TSEQ 2048
#define CDIM 1024
#define NHEADS 16
#define DHEAD 64
#define BSZ 2
#define MROWS (BSZ * TSEQ)  // 4096

typedef __attribute__((ext_vector_type(8))) short short8;
typedef __attribute__((ext_vector_type(4))) short short4v;
typedef __attribute__((ext_vector_type(4))) float f32x4;

__device__ inline f32x4 mfma16(short8 a, short8 b, f32x4 c) {
    return __builtin_amdgcn_mfma_f32_16x16x32_bf16(a, b, c, 0, 0, 0);
}

__device__ inline short f2bf(float f) {
    __hip_bfloat16 h = __float2bfloat16(f);
    return __builtin_bit_cast(short, h);
}
__device__ inline float bf2f(short s) {
    __hip_bfloat16 h = __builtin_bit_cast(__hip_bfloat16, s);
    return __bfloat162float(h);
}

// ---------------------------------------------------------------------------
// convx: f32 -> bf16 for x (4M elems).
// ---------------------------------------------------------------------------
__global__ __launch_bounds__(256) void convx_kernel(const float* __restrict__ x,
                                                    short* __restrict__ xb) {
    size_t off = (size_t)(blockIdx.x * 256 + threadIdx.x) * 8;
    float4 a = *(const float4*)(x + off);
    float4 b = *(const float4*)(x + off + 4);
    short8 h;
    h[0] = f2bf(a.x); h[1] = f2bf(a.y); h[2] = f2bf(a.z); h[3] = f2bf(a.w);
    h[4] = f2bf(b.x); h[5] = f2bf(b.y); h[6] = f2bf(b.z); h[7] = f2bf(b.w);
    *(short8*)(xb + off) = h;
}

// ---------------------------------------------------------------------------
// Fused QKV GEMM: BM=128, BN=128, BK=64, 4 waves (2x2), acc[4][4],
// T14 reg-prefetch (one K-step = ~600cy window). 16 barrier pairs.
// A bf16 from xb; B f32 weights, cvt at LDS-write. LDS rows 72 shorts
// (144B): all read/write patterns at full LDS BW.
// blockIdx.y: 0..23 -> which = y>>3 (0=Q,1=K,2=V), nbase = (y&7)*128.
// Q/K written UNSCALED [B,N,T,D] (attn applies 0.125). V transposed [B*N,D,T].
// ---------------------------------------------------------------------------
__global__ __launch_bounds__(256, 3) void gemm_qkv(
    const short* __restrict__ xb, const float* __restrict__ Wq,
    const float* __restrict__ Wk, const float* __restrict__ Wv,
    const float* __restrict__ bq, const float* __restrict__ bk,
    const float* __restrict__ bv, short* __restrict__ qws,
    short* __restrict__ kws, short* __restrict__ vtws) {
    __shared__ __attribute__((aligned(16))) short a_lds[128][72];
    __shared__ __attribute__((aligned(16))) short b_lds[128][72];

    const int tid = threadIdx.x;
    const int lane = tid & 63;
    const int wv = tid >> 6;
    const int wr = wv >> 1, wc = wv & 1;
    const int l15 = lane & 15, l4 = lane >> 4;
    const int mbase = blockIdx.x * 128;
    const int which = blockIdx.y >> 3;
    const int nbase = (blockIdx.y & 7) * 128;
    const float* Wf = which == 0 ? Wq : (which == 1 ? Wk : Wv);
    const float* bias = which == 0 ? bq : (which == 1 ? bk : bv);

    f32x4 acc[4][4];
#pragma unroll
    for (int i = 0; i < 4; ++i)
#pragma unroll
        for (int j = 0; j < 4; ++j) acc[i][j] = f32x4{0.f, 0.f, 0.f, 0.f};

    // staging: A 128x64 bf16 -> 4 short8/thread; B 128x64 f32 -> 8 float4/thread
    const int ar = tid >> 3;          // 0..31 (+32*it)
    const int ag = (tid & 7) * 8;     // short offset
    const int br = tid >> 4;          // 0..15 (+16*it)
    const int bg = (tid & 15) * 4;    // float offset
    const short* aptr = xb + (size_t)(mbase + ar) * CDIM + ag;
    const float* bptr = Wf + (size_t)(nbase + br) * CDIM + bg;

    short8 apre[4];
    float4 bpre[8];
#pragma unroll
    for (int it = 0; it < 4; ++it)
        apre[it] = *(const short8*)(aptr + (size_t)(32 * it) * CDIM);
#pragma unroll
    for (int it = 0; it < 8; ++it)
        bpre[it] = *(const float4*)(bptr + (size_t)(16 * it) * CDIM);

    for (int k0 = 0; k0 < CDIM; k0 += 64) {
        __syncthreads();  // prev iteration's ds_reads done
#pragma unroll
        for (int it = 0; it < 4; ++it)
            *(short8*)&a_lds[ar + 32 * it][ag] = apre[it];
#pragma unroll
        for (int it = 0; it < 8; ++it) {
            short4v h;
            h.x = f2bf(bpre[it].x); h.y = f2bf(bpre[it].y);
            h.z = f2bf(bpre[it].z); h.w = f2bf(bpre[it].w);
            *(short4v*)&b_lds[br + 16 * it][bg] = h;
        }
        __syncthreads();  // tile visible
        if (k0 + 64 < CDIM) {
#pragma unroll
            for (int it = 0; it < 4; ++it)
                apre[it] = *(const short8*)(aptr + (size_t)(32 * it) * CDIM + k0 + 64);
#pragma unroll
            for (int it = 0; it < 8; ++it)
                bpre[it] = *(const float4*)(bptr + (size_t)(16 * it) * CDIM + k0 + 64);
        }

#pragma unroll
        for (int kk = 0; kk < 2; ++kk) {
            short8 af[4], bfr[4];
#pragma unroll
            for (int i = 0; i < 4; ++i)
                af[i] = *(const short8*)&a_lds[wr * 64 + i * 16 + l15][kk * 32 + l4 * 8];
#pragma unroll
            for (int j = 0; j < 4; ++j)
                bfr[j] = *(const short8*)&b_lds[wc * 64 + j * 16 + l15][kk * 32 + l4 * 8];
#pragma unroll
            for (int i = 0; i < 4; ++i)
#pragma unroll
                for (int j = 0; j < 4; ++j)
                    acc[i][j] = mfma16(af[i], bfr[j], acc[i][j]);
        }
    }

    if (which < 2) {
        short* dst = which == 0 ? qws : kws;
#pragma unroll
        for (int i = 0; i < 4; ++i) {
            int mrow = mbase + wr * 64 + i * 16 + l4 * 4;
#pragma unroll
            for (int j = 0; j < 4; ++j) {
                int o = nbase + wc * 64 + j * 16 + l15;
                int n = o >> 6, d = o & 63;
                float bval = bias[o];
#pragma unroll
                for (int r = 0; r < 4; ++r) {
                    int mm = mrow + r;
                    int bb = mm >> 11;
                    int t = mm & (TSEQ - 1);
                    dst[(((size_t)bb * NHEADS + n) * TSEQ + t) * DHEAD + d] =
                        f2bf(acc[i][j][r] + bval);
                }
            }
        }
    } else {
#pragma unroll
        for (int i = 0; i < 4; ++i) {
            int mrow = mbase + wr * 64 + i * 16 + l4 * 4;
            int bb = mrow >> 11;
            int t = mrow & (TSEQ - 1);
#pragma unroll
            for (int j = 0; j < 4; ++j) {
                int o = nbase + wc * 64 + j * 16 + l15;
                int n = o >> 6, d = o & 63;
                float bval = bias[o];
                short4v h4;
#pragma unroll
                for (int r = 0; r < 4; ++r) h4[r] = f2bf(acc[i][j][r] + bval);
                *(short4v*)&vtws[(((size_t)bb * NHEADS + n) * DHEAD + d) * TSEQ + t] = h4;
            }
        }
    }
}

// ---------------------------------------------------------------------------
// Output projection GEMM (unchanged from passing r10): BM=64, BN=128, BK=32,
// T14 reg-prefetch. A = attn bf16, B = f32 Wp cvt at write. out f32 + bias.
// ---------------------------------------------------------------------------
__global__ __launch_bounds__(256) void gemm_p(
    const short* __restrict__ attn, const float* __restrict__ Wp,
    const float* __restrict__ bp, float* __restrict__ out) {
    __shared__ __attribute__((aligned(16))) short a_lds[64][40];
    __shared__ __attribute__((aligned(16))) short b_lds[128][40];

    const int tid = threadIdx.x;
    const int lane = tid & 63;
    const int wv = tid >> 6;
    const int wr = wv >> 1, wc = wv & 1;
    const int l15 = lane & 15, l4 = lane >> 4;
    const int mbase = blockIdx.x * 64;
    const int nbase = blockIdx.y * 128;

    f32x4 acc[2][4];
#pragma unroll
    for (int i = 0; i < 2; ++i)
#pragma unroll
        for (int j = 0; j < 4; ++j) acc[i][j] = f32x4{0.f, 0.f, 0.f, 0.f};

    const int arow = tid >> 2;
    const int acol = (tid & 3) * 8;
    const int brow = tid >> 3;
    const int bcol = (tid & 7) * 4;
    const short* aptr = attn + (size_t)(mbase + arow) * CDIM + acol;
    const float* bptr = Wp + (size_t)(nbase + brow) * CDIM + bcol;

    short8 apre;
    float4 bpre[4];
    apre = *(const short8*)(aptr);
#pragma unroll
    for (int it = 0; it < 4; ++it)
        bpre[it] = *(const float4*)(bptr + (size_t)(it * 32) * CDIM);

    for (int k0 = 0; k0 < CDIM; k0 += 32) {
        __syncthreads();
        *(short8*)&a_lds[arow][acol] = apre;
#pragma unroll
        for (int it = 0; it < 4; ++it) {
            short4v h;
            h.x = f2bf(bpre[it].x); h.y = f2bf(bpre[it].y);
            h.z = f2bf(bpre[it].z); h.w = f2bf(bpre[it].w);
            *(short4v*)&b_lds[brow + it * 32][bcol] = h;
        }
        __syncthreads();
        if (k0 + 32 < CDIM) {
            apre = *(const short8*)(aptr + k0 + 32);
#pragma unroll
            for (int it = 0; it < 4; ++it)
                bpre[it] = *(const float4*)(bptr + (size_t)(it * 32) * CDIM + k0 + 32);
        }

        short8 af[2], bfr[4];
#pragma unroll
        for (int i = 0; i < 2; ++i)
            af[i] = *(const short8*)&a_lds[wr * 32 + i * 16 + l15][l4 * 8];
#pragma unroll
        for (int j = 0; j < 4; ++j)
            bfr[j] = *(const short8*)&b_lds[wc * 64 + j * 16 + l15][l4 * 8];
#pragma unroll
        for (int i = 0; i < 2; ++i)
#pragma unroll
            for (int j = 0; j < 4; ++j)
                acc[i][j] = mfma16(af[i], bfr[j], acc[i][j]);
    }

#pragma unroll
    for (int i = 0; i < 2; ++i) {
        int mrow = mbase + wr * 32 + i * 16 + l4 * 4;
#pragma unroll
        for (int j = 0; j < 4; ++j) {
            int o = nbase + wc * 64 + j * 16 + l15;
            float bval = bp[o];
#pragma unroll
            for (int r = 0; r < 4; ++r)
                out[(size_t)(mrow + r) * CDIM + o] = acc[i][j][r] + bval;
        }
    }
}

// ---------------------------------------------------------------------------
// Flash attention v3: NO LDS staging, NO barriers. K/V fragments read
// directly from global (L1/L2-resident: 16KB/block working set; same-head
// blocks co-locate per XCD under %8 round-robin). Causal, QBLK=64 (4 waves
// x 16 q-rows), KVBLK=64, no-max softmax, deferred l-reduction.
// q,k bf16 [B*N,T,D]; vt bf16 [B*N,D,T]. p_lds wave-private.
// ---------------------------------------------------------------------------
__global__ __launch_bounds__(256) void attn_kernel(
    const short* __restrict__ q, const short* __restrict__ k,
    const short* __restrict__ vt, short* __restrict__ attn_out) {
    __shared__ __attribute__((aligned(16))) short p_lds[4][16][80];

    const int tid = threadIdx.x;
    const int w = tid >> 6;
    const int lane = tid & 63;
    const int l15 = lane & 15;
    const int l4 = lane >> 4;
    const int h = blockIdx.x;
    const int qtile = gridDim.y - 1 - blockIdx.y;   // heaviest first
    const int wrow0 = qtile * 64 + w * 16;

    // Q fragments (16 rows), pre-scaled by 1/sqrt(D)=0.125 (exact in bf16)
    short8 qf[2];
#pragma unroll
    for (int kh = 0; kh < 2; ++kh) {
        const short* qp = q + ((size_t)h * TSEQ + wrow0 + l15) * DHEAD + kh * 32 + l4 * 8;
        short8 t8 = *(const short8*)qp;
#pragma unroll
        for (int e = 0; e < 8; ++e) t8[e] = f2bf(bf2f(t8[e]) * 0.125f);
        qf[kh] = t8;
    }

    float l_run[4];
    f32x4 o_acc[4];
#pragma unroll
    for (int r = 0; r < 4; ++r) l_run[r] = 0.f;
#pragma unroll
    for (int dt = 0; dt < 4; ++dt) o_acc[dt] = f32x4{0.f, 0.f, 0.f, 0.f};

    const short* kbase = k + (size_t)h * TSEQ * DHEAD;
    const short* vbase = vt + (size_t)h * DHEAD * TSEQ;
    const int ntiles = qtile + 1;

    for (int kvt = 0; kvt < ntiles; ++kvt) {
        const int kvbase = kvt * 64;

        // S = Q K^T  (K fragments direct from global)
        f32x4 s[4];
#pragma unroll
        for (int jt = 0; jt < 4; ++jt) {
            const short* kr = kbase + (size_t)(kvbase + jt * 16 + l15) * DHEAD;
            short8 kf0 = *(const short8*)(kr + l4 * 8);
            short8 kf1 = *(const short8*)(kr + 32 + l4 * 8);
            f32x4 a = f32x4{0.f, 0.f, 0.f, 0.f};
            a = mfma16(qf[0], kf0, a);
            a = mfma16(qf[1], kf1, a);
            s[jt] = a;
        }

        // no-max softmax: p = exp(s), l accumulated (deferred reduce)
        const bool needmask = (kvbase + 63 > wrow0);
#pragma unroll
        for (int r = 0; r < 4; ++r) {
            int qrow = wrow0 + l4 * 4 + r;
            float lp = 0.f;
#pragma unroll
            for (int jt = 0; jt < 4; ++jt) {
                float x = s[jt][r];
                if (needmask && (kvbase + jt * 16 + l15 > qrow)) x = -INFINITY;
                float e = __expf(fminf(x, 60.f));
                lp += e;
                p_lds[w][l4 * 4 + r][jt * 16 + l15] = f2bf(e);
            }
            l_run[r] += lp;
        }

        // O += P @ V  (V^T fragments direct from global; p_lds wave-private)
        short8 pa0 = *(const short8*)&p_lds[w][l15][l4 * 8];
        short8 pa1 = *(const short8*)&p_lds[w][l15][32 + l4 * 8];
#pragma unroll
        for (int dt = 0; dt < 4; ++dt) {
            const short* vr = vbase + (size_t)(dt * 16 + l15) * TSEQ + kvbase;
            short8 vf0 = *(const short8*)(vr + l4 * 8);
            short8 vf1 = *(const short8*)(vr + 32 + l4 * 8);
            o_acc[dt] = mfma16(pa0, vf0, o_acc[dt]);
            o_acc[dt] = mfma16(pa1, vf1, o_acc[dt]);
        }
    }

    // epilogue: one l-reduction, then divide and store
#pragma unroll
    for (int r = 0; r < 4; ++r) {
        float l = l_run[r];
#pragma unroll
        for (int mk = 1; mk < 16; mk <<= 1) l += __shfl_xor(l, mk);
        l_run[r] = 1.0f / l;
    }
    const int b = h >> 4, n = h & 15;
#pragma unroll
    for (int dt = 0; dt < 4; ++dt) {
#pragma unroll
        for (int r = 0; r < 4; ++r) {
            int t = wrow0 + l4 * 4 + r;
            attn_out[((size_t)b * TSEQ + t) * CDIM + n * DHEAD + dt * 16 + l15] =
                f2bf(o_acc[dt][r] * l_run[r]);
        }
    }
}

extern "C" void kernel_launch(void* const* d_in, const int* in_sizes, int n_in,
                              void* d_out, int out_size, void* d_ws, size_t ws_size,
                              hipStream_t stream) {
    const float* x  = (const float*)d_in[0];
    const float* Wq = (const float*)d_in[1];
    const float* bq = (const float*)d_in[2];
    const float* Wk = (const float*)d_in[3];
    const float* bk = (const float*)d_in[4];
    const float* Wv = (const float*)d_in[5];
    const float* bv = (const float*)d_in[6];
    const float* Wp = (const float*)d_in[7];
    const float* bp = (const float*)d_in[8];

    char* ws = (char*)d_ws;
    const size_t SZ = (size_t)MROWS * CDIM * sizeof(short);  // 8 MB
    short* qws  = (short*)(ws);             // slot 0
    short* kws  = (short*)(ws + SZ);        // slot 1
    short* vtws = (short*)(ws + 2 * SZ);    // slot 2
    short* xb   = (short*)(ws + 3 * SZ);    // slot 3; reused for attn out
    short* attn = xb;                        // alias: xb dead after QKV GEMM

    convx_kernel<<<2048, 256, 0, stream>>>(x, xb);
    gemm_qkv<<<dim3(MROWS / 128, 24), 256, 0, stream>>>(xb, Wq, Wk, Wv, bq, bk, bv,
                                                         qws, kws, vtws);
    attn_kernel<<<dim3(BSZ * NHEADS, TSEQ / 64), 256, 0, stream>>>(qws, kws, vtws, attn);
    gemm_p<<<dim3(MROWS / 64, CDIM / 128), 256, 0, stream>>>(attn, Wp, bp, (float*)d_out);
}

// Round 12
// 113.874 us; speedup vs baseline: 1.8645x; 1.8645x over previous
//
#include <hip/hip_runtime.h>
#include <hip/hip_bf16.h>
#include <math.h>

#define TSEQ 2048
#define CDIM 1024
#define NHEADS 16
#define DHEAD 64
#define BSZ 2
#define MROWS (BSZ * TSEQ)  // 4096

typedef __attribute__((ext_vector_type(8))) short short8;
typedef __attribute__((ext_vector_type(4))) short short4v;
typedef __attribute__((ext_vector_type(4))) float f32x4;

__device__ inline f32x4 mfma16(short8 a, short8 b, f32x4 c) {
    return __builtin_amdgcn_mfma_f32_16x16x32_bf16(a, b, c, 0, 0, 0);
}

__device__ inline short f2bf(float f) {
    __hip_bfloat16 h = __float2bfloat16(f);
    return __builtin_bit_cast(short, h);
}
__device__ inline float bf2f(short s) {
    __hip_bfloat16 h = __builtin_bit_cast(__hip_bfloat16, s);
    return __bfloat162float(h);
}

// ---------------------------------------------------------------------------
// convx: f32 -> bf16 for x (4M elems).
// ---------------------------------------------------------------------------
__global__ __launch_bounds__(256) void convx_kernel(const float* __restrict__ x,
                                                    short* __restrict__ xb) {
    size_t off = (size_t)(blockIdx.x * 256 + threadIdx.x) * 8;
    float4 a = *(const float4*)(x + off);
    float4 b = *(const float4*)(x + off + 4);
    short8 h;
    h[0] = f2bf(a.x); h[1] = f2bf(a.y); h[2] = f2bf(a.z); h[3] = f2bf(a.w);
    h[4] = f2bf(b.x); h[5] = f2bf(b.y); h[6] = f2bf(b.z); h[7] = f2bf(b.w);
    *(short8*)(xb + off) = h;
}

// ---------------------------------------------------------------------------
// Fused QKV GEMM (unchanged from r11): BM=128, BN=128, BK=64, 4 waves,
// acc[4][4], T14 reg-prefetch, 16 barrier pairs. LDS rows 72 shorts.
// blockIdx.y: 0..23 -> which = y>>3 (0=Q,1=K,2=V), nbase = (y&7)*128.
// Q/K written UNSCALED [B,N,T,D] (attn applies 0.125). V transposed [B*N,D,T].
// ---------------------------------------------------------------------------
__global__ __launch_bounds__(256, 3) void gemm_qkv(
    const short* __restrict__ xb, const float* __restrict__ Wq,
    const float* __restrict__ Wk, const float* __restrict__ Wv,
    const float* __restrict__ bq, const float* __restrict__ bk,
    const float* __restrict__ bv, short* __restrict__ qws,
    short* __restrict__ kws, short* __restrict__ vtws) {
    __shared__ __attribute__((aligned(16))) short a_lds[128][72];
    __shared__ __attribute__((aligned(16))) short b_lds[128][72];

    const int tid = threadIdx.x;
    const int lane = tid & 63;
    const int wv = tid >> 6;
    const int wr = wv >> 1, wc = wv & 1;
    const int l15 = lane & 15, l4 = lane >> 4;
    const int mbase = blockIdx.x * 128;
    const int which = blockIdx.y >> 3;
    const int nbase = (blockIdx.y & 7) * 128;
    const float* Wf = which == 0 ? Wq : (which == 1 ? Wk : Wv);
    const float* bias = which == 0 ? bq : (which == 1 ? bk : bv);

    f32x4 acc[4][4];
#pragma unroll
    for (int i = 0; i < 4; ++i)
#pragma unroll
        for (int j = 0; j < 4; ++j) acc[i][j] = f32x4{0.f, 0.f, 0.f, 0.f};

    const int ar = tid >> 3;          // 0..31 (+32*it)
    const int ag = (tid & 7) * 8;
    const int br = tid >> 4;          // 0..15 (+16*it)
    const int bg = (tid & 15) * 4;
    const short* aptr = xb + (size_t)(mbase + ar) * CDIM + ag;
    const float* bptr = Wf + (size_t)(nbase + br) * CDIM + bg;

    short8 apre[4];
    float4 bpre[8];
#pragma unroll
    for (int it = 0; it < 4; ++it)
        apre[it] = *(const short8*)(aptr + (size_t)(32 * it) * CDIM);
#pragma unroll
    for (int it = 0; it < 8; ++it)
        bpre[it] = *(const float4*)(bptr + (size_t)(16 * it) * CDIM);

    for (int k0 = 0; k0 < CDIM; k0 += 64) {
        __syncthreads();
#pragma unroll
        for (int it = 0; it < 4; ++it)
            *(short8*)&a_lds[ar + 32 * it][ag] = apre[it];
#pragma unroll
        for (int it = 0; it < 8; ++it) {
            short4v h;
            h.x = f2bf(bpre[it].x); h.y = f2bf(bpre[it].y);
            h.z = f2bf(bpre[it].z); h.w = f2bf(bpre[it].w);
            *(short4v*)&b_lds[br + 16 * it][bg] = h;
        }
        __syncthreads();
        if (k0 + 64 < CDIM) {
#pragma unroll
            for (int it = 0; it < 4; ++it)
                apre[it] = *(const short8*)(aptr + (size_t)(32 * it) * CDIM + k0 + 64);
#pragma unroll
            for (int it = 0; it < 8; ++it)
                bpre[it] = *(const float4*)(bptr + (size_t)(16 * it) * CDIM + k0 + 64);
        }

#pragma unroll
        for (int kk = 0; kk < 2; ++kk) {
            short8 af[4], bfr[4];
#pragma unroll
            for (int i = 0; i < 4; ++i)
                af[i] = *(const short8*)&a_lds[wr * 64 + i * 16 + l15][kk * 32 + l4 * 8];
#pragma unroll
            for (int j = 0; j < 4; ++j)
                bfr[j] = *(const short8*)&b_lds[wc * 64 + j * 16 + l15][kk * 32 + l4 * 8];
#pragma unroll
            for (int i = 0; i < 4; ++i)
#pragma unroll
                for (int j = 0; j < 4; ++j)
                    acc[i][j] = mfma16(af[i], bfr[j], acc[i][j]);
        }
    }

    if (which < 2) {
        short* dst = which == 0 ? qws : kws;
#pragma unroll
        for (int i = 0; i < 4; ++i) {
            int mrow = mbase + wr * 64 + i * 16 + l4 * 4;
#pragma unroll
            for (int j = 0; j < 4; ++j) {
                int o = nbase + wc * 64 + j * 16 + l15;
                int n = o >> 6, d = o & 63;
                float bval = bias[o];
#pragma unroll
                for (int r = 0; r < 4; ++r) {
                    int mm = mrow + r;
                    int bb = mm >> 11;
                    int t = mm & (TSEQ - 1);
                    dst[(((size_t)bb * NHEADS + n) * TSEQ + t) * DHEAD + d] =
                        f2bf(acc[i][j][r] + bval);
                }
            }
        }
    } else {
#pragma unroll
        for (int i = 0; i < 4; ++i) {
            int mrow = mbase + wr * 64 + i * 16 + l4 * 4;
            int bb = mrow >> 11;
            int t = mrow & (TSEQ - 1);
#pragma unroll
            for (int j = 0; j < 4; ++j) {
                int o = nbase + wc * 64 + j * 16 + l15;
                int n = o >> 6, d = o & 63;
                float bval = bias[o];
                short4v h4;
#pragma unroll
                for (int r = 0; r < 4; ++r) h4[r] = f2bf(acc[i][j][r] + bval);
                *(short4v*)&vtws[(((size_t)bb * NHEADS + n) * DHEAD + d) * TSEQ + t] = h4;
            }
        }
    }
}

// ---------------------------------------------------------------------------
// Output projection GEMM (unchanged): BM=64, BN=128, BK=32, T14 prefetch.
// ---------------------------------------------------------------------------
__global__ __launch_bounds__(256) void gemm_p(
    const short* __restrict__ attn, const float* __restrict__ Wp,
    const float* __restrict__ bp, float* __restrict__ out) {
    __shared__ __attribute__((aligned(16))) short a_lds[64][40];
    __shared__ __attribute__((aligned(16))) short b_lds[128][40];

    const int tid = threadIdx.x;
    const int lane = tid & 63;
    const int wv = tid >> 6;
    const int wr = wv >> 1, wc = wv & 1;
    const int l15 = lane & 15, l4 = lane >> 4;
    const int mbase = blockIdx.x * 64;
    const int nbase = blockIdx.y * 128;

    f32x4 acc[2][4];
#pragma unroll
    for (int i = 0; i < 2; ++i)
#pragma unroll
        for (int j = 0; j < 4; ++j) acc[i][j] = f32x4{0.f, 0.f, 0.f, 0.f};

    const int arow = tid >> 2;
    const int acol = (tid & 3) * 8;
    const int brow = tid >> 3;
    const int bcol = (tid & 7) * 4;
    const short* aptr = attn + (size_t)(mbase + arow) * CDIM + acol;
    const float* bptr = Wp + (size_t)(nbase + brow) * CDIM + bcol;

    short8 apre;
    float4 bpre[4];
    apre = *(const short8*)(aptr);
#pragma unroll
    for (int it = 0; it < 4; ++it)
        bpre[it] = *(const float4*)(bptr + (size_t)(it * 32) * CDIM);

    for (int k0 = 0; k0 < CDIM; k0 += 32) {
        __syncthreads();
        *(short8*)&a_lds[arow][acol] = apre;
#pragma unroll
        for (int it = 0; it < 4; ++it) {
            short4v h;
            h.x = f2bf(bpre[it].x); h.y = f2bf(bpre[it].y);
            h.z = f2bf(bpre[it].z); h.w = f2bf(bpre[it].w);
            *(short4v*)&b_lds[brow + it * 32][bcol] = h;
        }
        __syncthreads();
        if (k0 + 32 < CDIM) {
            apre = *(const short8*)(aptr + k0 + 32);
#pragma unroll
            for (int it = 0; it < 4; ++it)
                bpre[it] = *(const float4*)(bptr + (size_t)(it * 32) * CDIM + k0 + 32);
        }

        short8 af[2], bfr[4];
#pragma unroll
        for (int i = 0; i < 2; ++i)
            af[i] = *(const short8*)&a_lds[wr * 32 + i * 16 + l15][l4 * 8];
#pragma unroll
        for (int j = 0; j < 4; ++j)
            bfr[j] = *(const short8*)&b_lds[wc * 64 + j * 16 + l15][l4 * 8];
#pragma unroll
        for (int i = 0; i < 2; ++i)
#pragma unroll
            for (int j = 0; j < 4; ++j)
                acc[i][j] = mfma16(af[i], bfr[j], acc[i][j]);
    }

#pragma unroll
    for (int i = 0; i < 2; ++i) {
        int mrow = mbase + wr * 32 + i * 16 + l4 * 4;
#pragma unroll
        for (int j = 0; j < 4; ++j) {
            int o = nbase + wc * 64 + j * 16 + l15;
            float bval = bp[o];
#pragma unroll
            for (int r = 0; r < 4; ++r)
                out[(size_t)(mrow + r) * CDIM + o] = acc[i][j][r] + bval;
        }
    }
}

// ---------------------------------------------------------------------------
// Flash attention (reverted to r10-passing version): causal, QBLK=64
// (4 waves x 16 q-rows), KVBLK=64, no-max softmax, deferred l-reduction,
// K/V reg-prefetch into XOR-swizzled LDS (group ^= row&7).
// q,k bf16 [B*N,T,D]; vt bf16 [B*N,D,T].
// ---------------------------------------------------------------------------
__global__ __launch_bounds__(256) void attn_kernel(
    const short* __restrict__ q, const short* __restrict__ k,
    const short* __restrict__ vt, short* __restrict__ attn_out) {
    __shared__ __attribute__((aligned(16))) short k_lds[64][64];
    __shared__ __attribute__((aligned(16))) short vt_lds[64][64];
    __shared__ __attribute__((aligned(16))) short p_lds[4][16][80];

    const int tid = threadIdx.x;
    const int w = tid >> 6;
    const int lane = tid & 63;
    const int l15 = lane & 15;
    const int l4 = lane >> 4;
    const int h = blockIdx.x;
    const int qtile = gridDim.y - 1 - blockIdx.y;
    const int qb = qtile * 64;
    const int wrow0 = qb + w * 16;

    short8 qf[2];
#pragma unroll
    for (int kh = 0; kh < 2; ++kh) {
        const short* qp = q + ((size_t)h * TSEQ + wrow0 + l15) * DHEAD + kh * 32 + l4 * 8;
        short8 t8 = *(const short8*)qp;
#pragma unroll
        for (int e = 0; e < 8; ++e) t8[e] = f2bf(bf2f(t8[e]) * 0.125f);
        qf[kh] = t8;
    }

    float l_run[4];
    f32x4 o_acc[4];
#pragma unroll
    for (int r = 0; r < 4; ++r) l_run[r] = 0.f;
#pragma unroll
    for (int dt = 0; dt < 4; ++dt) o_acc[dt] = f32x4{0.f, 0.f, 0.f, 0.f};

    const int ntiles = qtile + 1;
    const int srow = tid >> 3;
    const int sgrp = tid & 7;

    short8 kpre[2], vpre[2];
#pragma unroll
    for (int it = 0; it < 2; ++it) {
        int row = srow + it * 32;
        kpre[it] = *(const short8*)(k + ((size_t)h * TSEQ + row) * DHEAD + sgrp * 8);
        vpre[it] = *(const short8*)(vt + ((size_t)h * DHEAD + row) * TSEQ + sgrp * 8);
    }

    for (int kvt = 0; kvt < ntiles; ++kvt) {
        const int kvbase = kvt * 64;
        __syncthreads();
#pragma unroll
        for (int it = 0; it < 2; ++it) {
            int row = srow + it * 32;
            int gs = sgrp ^ (row & 7);
            *(short8*)&k_lds[row][gs * 8] = kpre[it];
            *(short8*)&vt_lds[row][gs * 8] = vpre[it];
        }
        __syncthreads();
        if (kvt + 1 < ntiles) {
            int kvb2 = kvbase + 64;
#pragma unroll
            for (int it = 0; it < 2; ++it) {
                int row = srow + it * 32;
                kpre[it] = *(const short8*)(k + ((size_t)h * TSEQ + kvb2 + row) * DHEAD + sgrp * 8);
                vpre[it] = *(const short8*)(vt + ((size_t)h * DHEAD + row) * TSEQ + kvb2 + sgrp * 8);
            }
        }

        f32x4 s[4];
#pragma unroll
        for (int jt = 0; jt < 4; ++jt) {
            int row = jt * 16 + l15;
            int sw = row & 7;
            short8 kf0 = *(const short8*)&k_lds[row][(l4 ^ sw) * 8];
            short8 kf1 = *(const short8*)&k_lds[row][((4 + l4) ^ sw) * 8];
            f32x4 a = f32x4{0.f, 0.f, 0.f, 0.f};
            a = mfma16(qf[0], kf0, a);
            a = mfma16(qf[1], kf1, a);
            s[jt] = a;
        }

        const bool needmask = (kvbase + 63 > wrow0);
#pragma unroll
        for (int r = 0; r < 4; ++r) {
            int qrow = wrow0 + l4 * 4 + r;
            float lp = 0.f;
#pragma unroll
            for (int jt = 0; jt < 4; ++jt) {
                float x = s[jt][r];
                if (needmask && (kvbase + jt * 16 + l15 > qrow)) x = -INFINITY;
                float e = __expf(fminf(x, 60.f));
                lp += e;
                p_lds[w][l4 * 4 + r][jt * 16 + l15] = f2bf(e);
            }
            l_run[r] += lp;
        }

        short8 pa0 = *(const short8*)&p_lds[w][l15][l4 * 8];
        short8 pa1 = *(const short8*)&p_lds[w][l15][32 + l4 * 8];
#pragma unroll
        for (int dt = 0; dt < 4; ++dt) {
            int row = dt * 16 + l15;
            int sw = row & 7;
            short8 vf0 = *(const short8*)&vt_lds[row][(l4 ^ sw) * 8];
            short8 vf1 = *(const short8*)&vt_lds[row][((4 + l4) ^ sw) * 8];
            o_acc[dt] = mfma16(pa0, vf0, o_acc[dt]);
            o_acc[dt] = mfma16(pa1, vf1, o_acc[dt]);
        }
    }

#pragma unroll
    for (int r = 0; r < 4; ++r) {
        float l = l_run[r];
#pragma unroll
        for (int mk = 1; mk < 16; mk <<= 1) l += __shfl_xor(l, mk);
        l_run[r] = 1.0f / l;
    }
    const int b = h >> 4, n = h & 15;
#pragma unroll
    for (int dt = 0; dt < 4; ++dt) {
#pragma unroll
        for (int r = 0; r < 4; ++r) {
            int t = wrow0 + l4 * 4 + r;
            attn_out[((size_t)b * TSEQ + t) * CDIM + n * DHEAD + dt * 16 + l15] =
                f2bf(o_acc[dt][r] * l_run[r]);
        }
    }
}

extern "C" void kernel_launch(void* const* d_in, const int* in_sizes, int n_in,
                              void* d_out, int out_size, void* d_ws, size_t ws_size,
                              hipStream_t stream) {
    const float* x  = (const float*)d_in[0];
    const float* Wq = (const float*)d_in[1];
    const float* bq = (const float*)d_in[2];
    const float* Wk = (const float*)d_in[3];
    const float* bk = (const float*)d_in[4];
    const float* Wv = (const float*)d_in[5];
    const float* bv = (const float*)d_in[6];
    const float* Wp = (const float*)d_in[7];
    const float* bp = (const float*)d_in[8];

    char* ws = (char*)d_ws;
    const size_t SZ = (size_t)MROWS * CDIM * sizeof(short);  // 8 MB
    short* qws  = (short*)(ws);             // slot 0
    short* kws  = (short*)(ws + SZ);        // slot 1
    short* vtws = (short*)(ws + 2 * SZ);    // slot 2
    short* xb   = (short*)(ws + 3 * SZ);    // slot 3; reused for attn out
    short* attn = xb;                        // alias: xb dead after QKV GEMM

    convx_kernel<<<2048, 256, 0, stream>>>(x, xb);
    gemm_qkv<<<dim3(MROWS / 128, 24), 256, 0, stream>>>(xb, Wq, Wk, Wv, bq, bk, bv,
                                                         qws, kws, vtws);
    attn_kernel<<<dim3(BSZ * NHEADS, TSEQ / 64), 256, 0, stream>>>(qws, kws, vtws, attn);
    gemm_p<<<dim3(MROWS / 64, CDIM / 128), 256, 0, stream>>>(attn, Wp, bp, (float*)d_out);
}